// Round 4
// baseline (352.090 us; speedup 1.0000x reference)
//
#include <hip/hip_runtime.h>
#include <math.h>

#define EPS 1e-4f
#define QAM_NORM 0.31622776601683794f  // 1/sqrt(10)

// One thread per site. Restructured for minimal live state:
//  - G is consumed (resid + A) and DIES before the Gauss-Jordan inverse
//  - mu via A^-1 algebra: mu_k = (1 - no*Re(Ainv_kk))/ev_k  (A = G*diag(ev)+no*I)
//  - llr_a re-loaded (L3-hot) for the final LLR phase; Kt recomputed there
// Peak live ~100 floats -> fits the 128-VGPR / 4-waves-per-SIMD bracket.
__global__ __launch_bounds__(256, 4) void siso_pic_kernel(
    const float* __restrict__ y,     // (S,16,2)
    const float* __restrict__ h,     // (S,16,4,2)
    const float* __restrict__ llr_a, // (S,4,4)
    const float* __restrict__ no_p,  // (1,)
    float* __restrict__ out,         // (S,4,4)
    int nsites)
{
    int site = blockIdx.x * blockDim.x + threadIdx.x;
    if (site >= nsites) return;
    const float no = no_p[0];

    // ---------------- phase 1: G = H^H H (upper) and y_mf = H^H y ---------
    float Gre[4][4], Gim[4][4];
    float ymf_re[4], ymf_im[4];
    #pragma unroll
    for (int i = 0; i < 4; i++) {
        ymf_re[i] = 0.f; ymf_im[i] = 0.f;
        #pragma unroll
        for (int j = 0; j < 4; j++) { Gre[i][j] = 0.f; Gim[i][j] = 0.f; }
    }
    const float4* hp = reinterpret_cast<const float4*>(h + (size_t)site * 128);
    const float4* yp = reinterpret_cast<const float4*>(y + (size_t)site * 32);
    #pragma unroll
    for (int m2 = 0; m2 < 8; m2++) {          // two antennas per step
        float4 yv2 = yp[m2];
        #pragma unroll
        for (int half = 0; half < 2; half++) {
            int m = 2 * m2 + half;
            float4 hA = hp[2 * m];
            float4 hB = hp[2 * m + 1];
            float hre[4] = {hA.x, hA.z, hB.x, hB.z};
            float him[4] = {hA.y, hA.w, hB.y, hB.w};
            float yr = half ? yv2.z : yv2.x;
            float yi = half ? yv2.w : yv2.y;
            #pragma unroll
            for (int i = 0; i < 4; i++) {
                ymf_re[i] += hre[i] * yr + him[i] * yi;
                ymf_im[i] += hre[i] * yi - him[i] * yr;
                #pragma unroll
                for (int j = i; j < 4; j++) {
                    Gre[i][j] += hre[i] * hre[j] + him[i] * him[j];
                    Gim[i][j] += hre[i] * him[j] - him[i] * hre[j];
                }
            }
        }
    }
    #pragma unroll
    for (int i = 0; i < 4; i++)
        #pragma unroll
        for (int j = 0; j < i; j++) { Gre[i][j] = Gre[j][i]; Gim[i][j] = -Gim[j][i]; }

    // ---------------- phase 2: priors -> sh, ev (llr regs die here) -------
    const float4* lp = reinterpret_cast<const float4*>(llr_a + (size_t)site * 16);
    float sh_re[4], sh_im[4], ev[4];
    #pragma unroll
    for (int k = 0; k < 4; k++) {
        float4 lv = lp[k];
        float lx[4] = {lv.x, lv.y, lv.z, lv.w};
        float p0[4];
        #pragma unroll
        for (int j = 0; j < 4; j++) {
            float x = lx[j];
            float ax = fabsf(x);
            float e = __expf(-ax);
            float r = 1.f / (1.f + e);
            p0[j] = (x >= 0.f) ? e * r : r;   // sigmoid(-x)
        }
        float t0 = 2.f * p0[0] - 1.f, t1 = 2.f * p0[1] - 1.f;
        float t2 = 2.f * p0[2] - 1.f, t3 = 2.f * p0[3] - 1.f;
        float sre = QAM_NORM * t0 * (2.f - t2);
        float sim = QAM_NORM * t1 * (2.f - t3);
        sh_re[k] = sre; sh_im[k] = sim;
        float p1_0 = 1.f - p0[0], p1_1 = 1.f - p0[1];
        float p1_2 = 1.f - p0[2], p1_3 = 1.f - p0[3];
        float pA[4] = { p0[0]*p0[1], p0[0]*p1_1, p1_0*p0[1], p1_0*p1_1 };
        float pB[4] = { p0[2]*p0[3], p0[2]*p1_3, p1_2*p0[3], p1_2*p1_3 };
        float e2 = 0.f;
        #pragma unroll
        for (int i = 0; i < 16; i++) {
            int b0 = (i >> 3) & 1, b1 = (i >> 2) & 1, b2 = (i >> 1) & 1, b3 = i & 1;
            float pr = (float)((1 - 2*b0) * (1 + 2*b2)) * QAM_NORM;
            float pi = (float)((1 - 2*b1) * (1 + 2*b3)) * QAM_NORM;
            float P = pA[(b0<<1)|b1] * pB[(b2<<1)|b3];
            float dr = sre - pr, di = sim - pi;
            float d2 = fmaxf(dr*dr + di*di, EPS*EPS);
            e2 += d2 * P;
        }
        ev[k] = e2;
    }

    // ---------------- phase 3: resid = ymf - G*sh (ymf dies) --------------
    float rr[4], ri[4];
    #pragma unroll
    for (int i = 0; i < 4; i++) {
        float ar = 0.f, ai = 0.f;
        #pragma unroll
        for (int j = 0; j < 4; j++) {
            ar += Gre[i][j] * sh_re[j] - Gim[i][j] * sh_im[j];
            ai += Gre[i][j] * sh_im[j] + Gim[i][j] * sh_re[j];
        }
        rr[i] = ymf_re[i] - ar; ri[i] = ymf_im[i] - ai;
    }

    // ---------------- phase 4: A = G*diag(ev) + no*I (G dies) -------------
    float Are[4][4], Aim[4][4];
    #pragma unroll
    for (int i = 0; i < 4; i++)
        #pragma unroll
        for (int j = 0; j < 4; j++) {
            Are[i][j] = Gre[i][j] * ev[j] + ((i == j) ? no : 0.f);
            Aim[i][j] = Gim[i][j] * ev[j];
        }

    // ---------------- phase 5: Gauss-Jordan inverse in place --------------
    #pragma unroll
    for (int p = 0; p < 4; p++) {
        float pr = Are[p][p], pi = Aim[p][p];
        float inv = 1.f / (pr * pr + pi * pi);
        float dre = pr * inv, dim = -pi * inv;
        Are[p][p] = 1.f; Aim[p][p] = 0.f;
        #pragma unroll
        for (int j = 0; j < 4; j++) {
            float ar = Are[p][j], ai = Aim[p][j];
            Are[p][j] = ar * dre - ai * dim;
            Aim[p][j] = ar * dim + ai * dre;
        }
        #pragma unroll
        for (int i = 0; i < 4; i++) {
            if (i == p) continue;
            float fr = Are[i][p], fi = Aim[i][p];
            Are[i][p] = 0.f; Aim[i][p] = 0.f;
            #pragma unroll
            for (int j = 0; j < 4; j++) {
                float br = Are[p][j], bi = Aim[p][j];
                Are[i][j] -= fr * br - fi * bi;
                Aim[i][j] -= fr * bi + fi * br;
            }
        }
    }

    // ---------------- phase 6: mu (via algebra), z, rho (A, sh, ev die) ---
    float z_re[4], z_im[4], rho[4];
    #pragma unroll
    for (int k = 0; k < 4; k++) {
        // mu_k = Re[(I - no*Ainv) diag(1/ev)]_kk  ==  Re(diag(Ainv*G))_kk
        float m = fmaxf((1.f - no * Are[k][k]) / ev[k], EPS);
        float wr = 0.f, wi = 0.f;
        #pragma unroll
        for (int j = 0; j < 4; j++) {
            wr += Are[k][j] * rr[j] - Aim[k][j] * ri[j];
            wi += Are[k][j] * ri[j] + Aim[k][j] * rr[j];
        }
        float minv = 1.f / m;
        z_re[k] = wr * minv + sh_re[k];
        z_im[k] = wi * minv + sh_im[k];
        rho[k] = m / fmaxf(1.f - ev[k] * m, EPS);
    }

    // ---------------- phase 7: reload llr (L3-hot), Kt, logsumexp ---------
    float4* op = reinterpret_cast<float4*>(out + (size_t)site * 16);
    #pragma unroll
    for (int k = 0; k < 4; k++) {
        float4 lv = lp[k];
        float l0 = lv.x, l1 = lv.y, l2 = lv.z, l3 = lv.w;
        float kt = 0.f;
        {
            float a0 = fabsf(l0), a1 = fabsf(l1), a2 = fabsf(l2), a3 = fabsf(l3);
            kt  = 0.5f*(a0+a1+a2+a3);
            kt += __logf(1.f + __expf(-a0)) + __logf(1.f + __expf(-a1))
                + __logf(1.f + __expf(-a2)) + __logf(1.f + __expf(-a3));
        }
        float dA[4] = { -0.5f*(l0+l1) - kt, -0.5f*(l0-l1) - kt,
                         0.5f*(l0-l1) - kt,  0.5f*(l0+l1) - kt };
        float dB[4] = { -0.5f*(l2+l3), -0.5f*(l2-l3),
                         0.5f*(l2-l3),  0.5f*(l2+l3) };
        float zr = z_re[k], zi = z_im[k], rh = rho[k];
        float ex[16];
        #pragma unroll
        for (int i = 0; i < 16; i++) {
            int b0 = (i >> 3) & 1, b1 = (i >> 2) & 1, b2 = (i >> 1) & 1, b3 = i & 1;
            float pr = (float)((1 - 2*b0) * (1 + 2*b2)) * QAM_NORM;
            float pi = (float)((1 - 2*b1) * (1 + 2*b3)) * QAM_NORM;
            float dr = zr - pr, di = zi - pi;
            float d2 = fmaxf(dr*dr + di*di, EPS*EPS);
            ex[i] = -d2 * rh + dA[(b0<<1)|b1] + dB[(b2<<1)|b3];
        }
        float res[4];
        #pragma unroll
        for (int j = 0; j < 4; j++) {
            float m1 = -1e30f, m0 = -1e30f;
            #pragma unroll
            for (int i = 0; i < 16; i++) {
                if ((i >> (3 - j)) & 1) m1 = fmaxf(m1, ex[i]);
                else                    m0 = fmaxf(m0, ex[i]);
            }
            float s1 = 0.f, s0 = 0.f;
            #pragma unroll
            for (int i = 0; i < 16; i++) {
                if ((i >> (3 - j)) & 1) s1 += __expf(ex[i] - m1);
                else                    s0 += __expf(ex[i] - m0);
            }
            res[j] = (m1 - m0) + (__logf(s1) - __logf(s0));
        }
        op[k] = make_float4(res[0], res[1], res[2], res[3]);
    }
}

extern "C" void kernel_launch(void* const* d_in, const int* in_sizes, int n_in,
                              void* d_out, int out_size, void* d_ws, size_t ws_size,
                              hipStream_t stream) {
    const float* y    = (const float*)d_in[0];
    const float* h    = (const float*)d_in[1];
    const float* llr  = (const float*)d_in[2];
    const float* no   = (const float*)d_in[3];
    float* out = (float*)d_out;
    int nsites = in_sizes[2] / 16;   // B*T*S = 196608
    int threads = 256;
    int blocks = (nsites + threads - 1) / threads;
    siso_pic_kernel<<<blocks, threads, 0, stream>>>(y, h, llr, no, out, nsites);
}

// Round 5
// 241.103 us; speedup vs baseline: 1.4603x; 1.4603x over previous
//
#include <hip/hip_runtime.h>
#include <math.h>

#define EPS 1e-4f
#define QAM_NORM 0.31622776601683794f  // 1/sqrt(10)

// TWO lanes per site (lane pair 2s,2s+1 in the same wave).
//  phase 1: each lane accumulates G/y_mf over 8 of 16 antennas, then a
//           24-float __shfl_xor(.,1) pairwise reduce gives both lanes full G.
//  back end: each lane owns 2 of 4 streams; GJ inverse redundant per lane.
//  All register arrays use compile-time indices only (no scratch).
//  NO min-waves launch bound: forcing one produced 600MB of spill traffic (R3/R4).
__global__ __launch_bounds__(256) void siso_pic_kernel(
    const float* __restrict__ y,     // (S,16,2)
    const float* __restrict__ h,     // (S,16,4,2)
    const float* __restrict__ llr_a, // (S,4,4)
    const float* __restrict__ no_p,  // (1,)
    float* __restrict__ out,         // (S,4,4)
    int nsites)
{
    int tid = blockIdx.x * blockDim.x + threadIdx.x;
    int site = tid >> 1;
    int half = tid & 1;                 // 0: antennas 0-7, streams 0,1 ; 1: antennas 8-15, streams 2,3
    if (site >= nsites) return;
    const float no = no_p[0];

    // ---------------- phase 1: partial G = H^H H, y_mf = H^H y (8 antennas) ----
    float Gre[4][4], Gim[4][4];
    float ymf_re[4], ymf_im[4];
    #pragma unroll
    for (int i = 0; i < 4; i++) {
        ymf_re[i] = 0.f; ymf_im[i] = 0.f;
        #pragma unroll
        for (int j = 0; j < 4; j++) { Gre[i][j] = 0.f; Gim[i][j] = 0.f; }
    }
    const float4* hpl = reinterpret_cast<const float4*>(h + (size_t)site * 128) + half * 16;
    const float4* ypl = reinterpret_cast<const float4*>(y + (size_t)site * 32) + half * 4;
    #pragma unroll
    for (int mm = 0; mm < 4; mm++) {       // 2 antennas per step, 8 total
        float4 yv2 = ypl[mm];
        #pragma unroll
        for (int h2 = 0; h2 < 2; h2++) {
            int ml = 2 * mm + h2;
            float4 hA = hpl[2 * ml];
            float4 hB = hpl[2 * ml + 1];
            float hre[4] = {hA.x, hA.z, hB.x, hB.z};
            float him[4] = {hA.y, hA.w, hB.y, hB.w};
            float yr = h2 ? yv2.z : yv2.x;
            float yi = h2 ? yv2.w : yv2.y;
            #pragma unroll
            for (int i = 0; i < 4; i++) {
                ymf_re[i] += hre[i] * yr + him[i] * yi;
                ymf_im[i] += hre[i] * yi - him[i] * yr;
                #pragma unroll
                for (int j = i; j < 4; j++) {
                    Gre[i][j] += hre[i] * hre[j] + him[i] * him[j];
                    Gim[i][j] += hre[i] * him[j] - him[i] * hre[j];
                }
            }
        }
    }
    // pairwise combine (lane 2s holds antennas 0-7, lane 2s+1 holds 8-15)
    #pragma unroll
    for (int i = 0; i < 4; i++) {
        ymf_re[i] += __shfl_xor(ymf_re[i], 1);
        ymf_im[i] += __shfl_xor(ymf_im[i], 1);
        #pragma unroll
        for (int j = i; j < 4; j++) {
            Gre[i][j] += __shfl_xor(Gre[i][j], 1);
            if (j > i) Gim[i][j] += __shfl_xor(Gim[i][j], 1);
            else       Gim[i][j] = 0.f;    // exact zero on diagonal
        }
    }
    #pragma unroll
    for (int i = 0; i < 4; i++)
        #pragma unroll
        for (int j = 0; j < i; j++) { Gre[i][j] = Gre[j][i]; Gim[i][j] = -Gim[j][i]; }

    // ---------------- phase 2: priors for OWN 2 streams -> sh, ev --------------
    const float4* lp = reinterpret_cast<const float4*>(llr_a + (size_t)site * 16);
    int k0 = half * 2;
    float shr_own[2], shi_own[2], ev_own[2];
    #pragma unroll
    for (int kk = 0; kk < 2; kk++) {
        float4 lv = lp[k0 + kk];
        float lx[4] = {lv.x, lv.y, lv.z, lv.w};
        float p0[4];
        #pragma unroll
        for (int j = 0; j < 4; j++) {
            float x = lx[j];
            float ax = fabsf(x);
            float e = __expf(-ax);
            float r = 1.f / (1.f + e);
            p0[j] = (x >= 0.f) ? e * r : r;   // sigmoid(-x)
        }
        float t0 = 2.f * p0[0] - 1.f, t1 = 2.f * p0[1] - 1.f;
        float t2 = 2.f * p0[2] - 1.f, t3 = 2.f * p0[3] - 1.f;
        float sre = QAM_NORM * t0 * (2.f - t2);
        float sim = QAM_NORM * t1 * (2.f - t3);
        shr_own[kk] = sre; shi_own[kk] = sim;
        float p1_0 = 1.f - p0[0], p1_1 = 1.f - p0[1];
        float p1_2 = 1.f - p0[2], p1_3 = 1.f - p0[3];
        float pA[4] = { p0[0]*p0[1], p0[0]*p1_1, p1_0*p0[1], p1_0*p1_1 };
        float pB[4] = { p0[2]*p0[3], p0[2]*p1_3, p1_2*p0[3], p1_2*p1_3 };
        float e2 = 0.f;
        #pragma unroll
        for (int i = 0; i < 16; i++) {
            int b0 = (i >> 3) & 1, b1 = (i >> 2) & 1, b2 = (i >> 1) & 1, b3 = i & 1;
            float pr = (float)((1 - 2*b0) * (1 + 2*b2)) * QAM_NORM;
            float pi = (float)((1 - 2*b1) * (1 + 2*b3)) * QAM_NORM;
            float P = pA[(b0<<1)|b1] * pB[(b2<<1)|b3];
            float dr = sre - pr, di = sim - pi;
            float d2 = fmaxf(dr*dr + di*di, EPS*EPS);
            e2 += d2 * P;
        }
        ev_own[kk] = e2;
    }
    // exchange -> full sh[4], ev[4] (static indices via selects)
    float o_sr0 = __shfl_xor(shr_own[0], 1), o_sr1 = __shfl_xor(shr_own[1], 1);
    float o_si0 = __shfl_xor(shi_own[0], 1), o_si1 = __shfl_xor(shi_own[1], 1);
    float o_ev0 = __shfl_xor(ev_own[0], 1),  o_ev1 = __shfl_xor(ev_own[1], 1);
    float sh_re[4], sh_im[4], ev4[4];
    sh_re[0] = half ? o_sr0 : shr_own[0];  sh_re[1] = half ? o_sr1 : shr_own[1];
    sh_re[2] = half ? shr_own[0] : o_sr0;  sh_re[3] = half ? shr_own[1] : o_sr1;
    sh_im[0] = half ? o_si0 : shi_own[0];  sh_im[1] = half ? o_si1 : shi_own[1];
    sh_im[2] = half ? shi_own[0] : o_si0;  sh_im[3] = half ? shi_own[1] : o_si1;
    ev4[0]   = half ? o_ev0 : ev_own[0];   ev4[1]   = half ? o_ev1 : ev_own[1];
    ev4[2]   = half ? ev_own[0] : o_ev0;   ev4[3]   = half ? ev_own[1] : o_ev1;

    // ---------------- phase 3: resid = ymf - G*sh (ymf dies) -------------------
    float rr[4], ri[4];
    #pragma unroll
    for (int i = 0; i < 4; i++) {
        float ar = 0.f, ai = 0.f;
        #pragma unroll
        for (int j = 0; j < 4; j++) {
            ar += Gre[i][j] * sh_re[j] - Gim[i][j] * sh_im[j];
            ai += Gre[i][j] * sh_im[j] + Gim[i][j] * sh_re[j];
        }
        rr[i] = ymf_re[i] - ar; ri[i] = ymf_im[i] - ai;
    }

    // ---------------- phase 4: A = G*diag(ev) + no*I (G dies) ------------------
    float Are[4][4], Aim[4][4];
    #pragma unroll
    for (int i = 0; i < 4; i++)
        #pragma unroll
        for (int j = 0; j < 4; j++) {
            Are[i][j] = Gre[i][j] * ev4[j] + ((i == j) ? no : 0.f);
            Aim[i][j] = Gim[i][j] * ev4[j];
        }

    // ---------------- phase 5: Gauss-Jordan inverse (redundant per lane) -------
    #pragma unroll
    for (int p = 0; p < 4; p++) {
        float pr = Are[p][p], pi = Aim[p][p];
        float inv = 1.f / (pr * pr + pi * pi);
        float dre = pr * inv, dim = -pi * inv;
        Are[p][p] = 1.f; Aim[p][p] = 0.f;
        #pragma unroll
        for (int j = 0; j < 4; j++) {
            float ar = Are[p][j], ai = Aim[p][j];
            Are[p][j] = ar * dre - ai * dim;
            Aim[p][j] = ar * dim + ai * dre;
        }
        #pragma unroll
        for (int i = 0; i < 4; i++) {
            if (i == p) continue;
            float fr = Are[i][p], fi = Aim[i][p];
            Are[i][p] = 0.f; Aim[i][p] = 0.f;
            #pragma unroll
            for (int j = 0; j < 4; j++) {
                float br = Are[p][j], bi = Aim[p][j];
                Are[i][j] -= fr * br - fi * bi;
                Aim[i][j] -= fr * bi + fi * br;
            }
        }
    }

    // ---------------- phase 6+7: own 2 streams: mu, z, rho, logsumexp ----------
    float4* op = reinterpret_cast<float4*>(out + (size_t)site * 16);
    #pragma unroll
    for (int kk = 0; kk < 2; kk++) {
        // own row of Ainv (static indices in both select arms)
        float Ar[4], Ai[4];
        #pragma unroll
        for (int j = 0; j < 4; j++) {
            Ar[j] = half ? Are[2 + kk][j] : Are[kk][j];
            Ai[j] = half ? Aim[2 + kk][j] : Aim[kk][j];
        }
        float diag = kk ? (half ? Ar[3] : Ar[1]) : (half ? Ar[2] : Ar[0]);
        float evk  = ev_own[kk];
        // mu_k = (1 - no*Re(Ainv_kk)) / ev_k   [= Re(diag(Ainv*G))_kk]
        float m = fmaxf((1.f - no * diag) / evk, EPS);
        float wr = 0.f, wi = 0.f;
        #pragma unroll
        for (int j = 0; j < 4; j++) {
            wr += Ar[j] * rr[j] - Ai[j] * ri[j];
            wi += Ar[j] * ri[j] + Ai[j] * rr[j];
        }
        float minv = 1.f / m;
        float zr = wr * minv + shr_own[kk];
        float zi = wi * minv + shi_own[kk];
        float rh = m / fmaxf(1.f - evk * m, EPS);

        // reload own llr (L3-hot), recompute Kt
        float4 lv = lp[k0 + kk];
        float l0 = lv.x, l1 = lv.y, l2 = lv.z, l3 = lv.w;
        float a0 = fabsf(l0), a1 = fabsf(l1), a2 = fabsf(l2), a3 = fabsf(l3);
        float kt = 0.5f*(a0+a1+a2+a3)
                 + __logf(1.f + __expf(-a0)) + __logf(1.f + __expf(-a1))
                 + __logf(1.f + __expf(-a2)) + __logf(1.f + __expf(-a3));
        float dA[4] = { -0.5f*(l0+l1) - kt, -0.5f*(l0-l1) - kt,
                         0.5f*(l0-l1) - kt,  0.5f*(l0+l1) - kt };
        float dB[4] = { -0.5f*(l2+l3), -0.5f*(l2-l3),
                         0.5f*(l2-l3),  0.5f*(l2+l3) };
        float ex[16];
        #pragma unroll
        for (int i = 0; i < 16; i++) {
            int b0 = (i >> 3) & 1, b1 = (i >> 2) & 1, b2 = (i >> 1) & 1, b3 = i & 1;
            float pr = (float)((1 - 2*b0) * (1 + 2*b2)) * QAM_NORM;
            float pi = (float)((1 - 2*b1) * (1 + 2*b3)) * QAM_NORM;
            float dr = zr - pr, di = zi - pi;
            float d2 = fmaxf(dr*dr + di*di, EPS*EPS);
            ex[i] = -d2 * rh + dA[(b0<<1)|b1] + dB[(b2<<1)|b3];
        }
        float res[4];
        #pragma unroll
        for (int j = 0; j < 4; j++) {
            float m1 = -1e30f, m0 = -1e30f;
            #pragma unroll
            for (int i = 0; i < 16; i++) {
                if ((i >> (3 - j)) & 1) m1 = fmaxf(m1, ex[i]);
                else                    m0 = fmaxf(m0, ex[i]);
            }
            float s1 = 0.f, s0 = 0.f;
            #pragma unroll
            for (int i = 0; i < 16; i++) {
                if ((i >> (3 - j)) & 1) s1 += __expf(ex[i] - m1);
                else                    s0 += __expf(ex[i] - m0);
            }
            res[j] = (m1 - m0) + (__logf(s1) - __logf(s0));
        }
        op[k0 + kk] = make_float4(res[0], res[1], res[2], res[3]);
    }
}

extern "C" void kernel_launch(void* const* d_in, const int* in_sizes, int n_in,
                              void* d_out, int out_size, void* d_ws, size_t ws_size,
                              hipStream_t stream) {
    const float* y    = (const float*)d_in[0];
    const float* h    = (const float*)d_in[1];
    const float* llr  = (const float*)d_in[2];
    const float* no   = (const float*)d_in[3];
    float* out = (float*)d_out;
    int nsites = in_sizes[2] / 16;   // B*T*S = 196608
    int threads = 256;
    long long total = 2LL * nsites;  // 2 lanes per site
    int blocks = (int)((total + threads - 1) / threads);
    siso_pic_kernel<<<blocks, threads, 0, stream>>>(y, h, llr, no, out, nsites);
}

// Round 6
// 184.079 us; speedup vs baseline: 1.9127x; 1.3098x over previous
//
#include <hip/hip_runtime.h>
#include <math.h>

#define EPS 1e-4f
#define QAM_NORM 0.31622776601683794f  // 1/sqrt(10)

// FOUR lanes per site (lane group of 4 within a wave).
//  - lane g owns antennas {g, g+4, g+8, g+12}: 4x fewer loads/thread, denser
//    per-instruction address pattern (32B stride / 16B dense within group).
//  - G/y_mf pairwise-reduced across the 4 lanes via __shfl_xor(1)+__shfl_xor(2).
//  - lane g owns stream k=g end-to-end: prior, ev, mu/z/rho, full 16-pt lse.
//  - GJ inverse of the 4x4 complex A is computed redundantly per lane (~300 VALU).
//  - All register arrays compile-time indexed; cross-lane state via shuffles only.
//  - NO min-waves launch bound (R3/R4: forcing one causes catastrophic spills).
__global__ __launch_bounds__(256) void siso_pic_kernel(
    const float* __restrict__ y,     // (S,16,2)
    const float* __restrict__ h,     // (S,16,4,2)
    const float* __restrict__ llr_a, // (S,4,4)
    const float* __restrict__ no_p,  // (1,)
    float* __restrict__ out,         // (S,4,4)
    int nsites)
{
    int tid = blockIdx.x * blockDim.x + threadIdx.x;
    int site = tid >> 2;
    int g = tid & 3;                  // lane's stream + antenna-phase
    if (site >= nsites) return;
    int wl = threadIdx.x & 63;
    int gb = wl & ~3;                 // 4-lane group base within wave
    const float no = no_p[0];

    // ---------------- phase 1: partial G, y_mf over own 4 antennas -------------
    float Gre[4][4], Gim[4][4];
    float ymf_re[4], ymf_im[4];
    #pragma unroll
    for (int i = 0; i < 4; i++) {
        ymf_re[i] = 0.f; ymf_im[i] = 0.f;
        #pragma unroll
        for (int j = 0; j < 4; j++) { Gre[i][j] = 0.f; Gim[i][j] = 0.f; }
    }
    const float4* hp = reinterpret_cast<const float4*>(h + (size_t)site * 128);
    const float2* yp = reinterpret_cast<const float2*>(y + (size_t)site * 32);
    #pragma unroll
    for (int mm = 0; mm < 4; mm++) {
        int m = 4 * mm + g;           // own antenna
        float4 hA = hp[2 * m];        // streams 0,1 (re,im each)
        float4 hB = hp[2 * m + 1];    // streams 2,3
        float2 yv = yp[m];
        float hre[4] = {hA.x, hA.z, hB.x, hB.z};
        float him[4] = {hA.y, hA.w, hB.y, hB.w};
        #pragma unroll
        for (int i = 0; i < 4; i++) {
            ymf_re[i] += hre[i] * yv.x + him[i] * yv.y;
            ymf_im[i] += hre[i] * yv.y - him[i] * yv.x;
            #pragma unroll
            for (int j = i; j < 4; j++) {
                Gre[i][j] += hre[i] * hre[j] + him[i] * him[j];
                Gim[i][j] += hre[i] * him[j] - him[i] * hre[j];
            }
        }
    }
    // butterfly reduce across the 4-lane group (xor 1, then xor 2)
    #pragma unroll
    for (int i = 0; i < 4; i++) {
        ymf_re[i] += __shfl_xor(ymf_re[i], 1); ymf_re[i] += __shfl_xor(ymf_re[i], 2);
        ymf_im[i] += __shfl_xor(ymf_im[i], 1); ymf_im[i] += __shfl_xor(ymf_im[i], 2);
        #pragma unroll
        for (int j = i; j < 4; j++) {
            Gre[i][j] += __shfl_xor(Gre[i][j], 1); Gre[i][j] += __shfl_xor(Gre[i][j], 2);
            if (j > i) { Gim[i][j] += __shfl_xor(Gim[i][j], 1); Gim[i][j] += __shfl_xor(Gim[i][j], 2); }
            else         Gim[i][j] = 0.f;
        }
    }
    #pragma unroll
    for (int i = 0; i < 4; i++)
        #pragma unroll
        for (int j = 0; j < i; j++) { Gre[i][j] = Gre[j][i]; Gim[i][j] = -Gim[j][i]; }

    // ---------------- phase 2: prior for OWN stream -> sh, ev ------------------
    const float4 lv = reinterpret_cast<const float4*>(llr_a + (size_t)site * 16)[g];
    float shr_own, shi_own, ev_own;
    {
        float lx[4] = {lv.x, lv.y, lv.z, lv.w};
        float p0[4];
        #pragma unroll
        for (int j = 0; j < 4; j++) {
            float x = lx[j];
            float ax = fabsf(x);
            float e = __expf(-ax);
            float r = 1.f / (1.f + e);
            p0[j] = (x >= 0.f) ? e * r : r;   // sigmoid(-x)
        }
        float t0 = 2.f * p0[0] - 1.f, t1 = 2.f * p0[1] - 1.f;
        float t2 = 2.f * p0[2] - 1.f, t3 = 2.f * p0[3] - 1.f;
        shr_own = QAM_NORM * t0 * (2.f - t2);
        shi_own = QAM_NORM * t1 * (2.f - t3);
        float p1_0 = 1.f - p0[0], p1_1 = 1.f - p0[1];
        float p1_2 = 1.f - p0[2], p1_3 = 1.f - p0[3];
        float pA[4] = { p0[0]*p0[1], p0[0]*p1_1, p1_0*p0[1], p1_0*p1_1 };
        float pB[4] = { p0[2]*p0[3], p0[2]*p1_3, p1_2*p0[3], p1_2*p1_3 };
        float e2 = 0.f;
        #pragma unroll
        for (int i = 0; i < 16; i++) {
            int b0 = (i >> 3) & 1, b1 = (i >> 2) & 1, b2 = (i >> 1) & 1, b3 = i & 1;
            float pr = (float)((1 - 2*b0) * (1 + 2*b2)) * QAM_NORM;
            float pi = (float)((1 - 2*b1) * (1 + 2*b3)) * QAM_NORM;
            float P = pA[(b0<<1)|b1] * pB[(b2<<1)|b3];
            float dr = shr_own - pr, di = shi_own - pi;
            float d2 = fmaxf(dr*dr + di*di, EPS*EPS);
            e2 += d2 * P;
        }
        ev_own = e2;
    }
    // gather full sh[4], ev[4] from the group
    float sh_re[4], sh_im[4], ev4[4];
    #pragma unroll
    for (int j = 0; j < 4; j++) {
        sh_re[j] = __shfl(shr_own, gb + j);
        sh_im[j] = __shfl(shi_own, gb + j);
        ev4[j]   = __shfl(ev_own,  gb + j);
    }

    // ---------------- phase 3: resid = ymf - G*sh (ymf dies) -------------------
    float rr[4], ri[4];
    #pragma unroll
    for (int i = 0; i < 4; i++) {
        float ar = 0.f, ai = 0.f;
        #pragma unroll
        for (int j = 0; j < 4; j++) {
            ar += Gre[i][j] * sh_re[j] - Gim[i][j] * sh_im[j];
            ai += Gre[i][j] * sh_im[j] + Gim[i][j] * sh_re[j];
        }
        rr[i] = ymf_re[i] - ar; ri[i] = ymf_im[i] - ai;
    }

    // ---------------- phase 4: A = G*diag(ev) + no*I (G dies) ------------------
    float Are[4][4], Aim[4][4];
    #pragma unroll
    for (int i = 0; i < 4; i++)
        #pragma unroll
        for (int j = 0; j < 4; j++) {
            Are[i][j] = Gre[i][j] * ev4[j] + ((i == j) ? no : 0.f);
            Aim[i][j] = Gim[i][j] * ev4[j];
        }

    // ---------------- phase 5: Gauss-Jordan inverse (redundant per lane) -------
    #pragma unroll
    for (int p = 0; p < 4; p++) {
        float pr = Are[p][p], pi = Aim[p][p];
        float inv = 1.f / (pr * pr + pi * pi);
        float dre = pr * inv, dim = -pi * inv;
        Are[p][p] = 1.f; Aim[p][p] = 0.f;
        #pragma unroll
        for (int j = 0; j < 4; j++) {
            float ar = Are[p][j], ai = Aim[p][j];
            Are[p][j] = ar * dre - ai * dim;
            Aim[p][j] = ar * dim + ai * dre;
        }
        #pragma unroll
        for (int i = 0; i < 4; i++) {
            if (i == p) continue;
            float fr = Are[i][p], fi = Aim[i][p];
            Are[i][p] = 0.f; Aim[i][p] = 0.f;
            #pragma unroll
            for (int j = 0; j < 4; j++) {
                float br = Are[p][j], bi = Aim[p][j];
                Are[i][j] -= fr * br - fi * bi;
                Aim[i][j] -= fr * bi + fi * br;
            }
        }
    }

    // ---------------- phase 6: own row of Ainv -> mu, z, rho -------------------
    float Ar[4], Ai[4];
    #pragma unroll
    for (int j = 0; j < 4; j++) {
        float a0 = Are[0][j], a1 = Are[1][j], a2 = Are[2][j], a3 = Are[3][j];
        float b0 = Aim[0][j], b1 = Aim[1][j], b2 = Aim[2][j], b3 = Aim[3][j];
        Ar[j] = (g == 0) ? a0 : (g == 1) ? a1 : (g == 2) ? a2 : a3;
        Ai[j] = (g == 0) ? b0 : (g == 1) ? b1 : (g == 2) ? b2 : b3;
    }
    float diag = (g == 0) ? Are[0][0] : (g == 1) ? Are[1][1]
               : (g == 2) ? Are[2][2] : Are[3][3];
    // mu_k = (1 - no*Re(Ainv_kk))/ev_k  [= Re(diag(Ainv*G))_kk, A = G*diag(ev)+no*I]
    float m = fmaxf((1.f - no * diag) / ev_own, EPS);
    float wr = 0.f, wi = 0.f;
    #pragma unroll
    for (int j = 0; j < 4; j++) {
        wr += Ar[j] * rr[j] - Ai[j] * ri[j];
        wi += Ar[j] * ri[j] + Ai[j] * rr[j];
    }
    float minv = 1.f / m;
    float zr = wr * minv + shr_own;
    float zi = wi * minv + shi_own;
    float rh = m / fmaxf(1.f - ev_own * m, EPS);

    // ---------------- phase 7: exponents + per-bit logsumexp (own stream) ------
    float l0 = lv.x, l1 = lv.y, l2 = lv.z, l3 = lv.w;
    float a0 = fabsf(l0), a1 = fabsf(l1), a2 = fabsf(l2), a3 = fabsf(l3);
    float kt = 0.5f*(a0+a1+a2+a3)
             + __logf(1.f + __expf(-a0)) + __logf(1.f + __expf(-a1))
             + __logf(1.f + __expf(-a2)) + __logf(1.f + __expf(-a3));
    float dA[4] = { -0.5f*(l0+l1) - kt, -0.5f*(l0-l1) - kt,
                     0.5f*(l0-l1) - kt,  0.5f*(l0+l1) - kt };
    float dB[4] = { -0.5f*(l2+l3), -0.5f*(l2-l3),
                     0.5f*(l2-l3),  0.5f*(l2+l3) };
    float ex[16];
    #pragma unroll
    for (int i = 0; i < 16; i++) {
        int b0 = (i >> 3) & 1, b1 = (i >> 2) & 1, b2 = (i >> 1) & 1, b3 = i & 1;
        float pr = (float)((1 - 2*b0) * (1 + 2*b2)) * QAM_NORM;
        float pi = (float)((1 - 2*b1) * (1 + 2*b3)) * QAM_NORM;
        float dr = zr - pr, di = zi - pi;
        float d2 = fmaxf(dr*dr + di*di, EPS*EPS);
        ex[i] = -d2 * rh + dA[(b0<<1)|b1] + dB[(b2<<1)|b3];
    }
    float res[4];
    #pragma unroll
    for (int j = 0; j < 4; j++) {
        float m1 = -1e30f, m0 = -1e30f;
        #pragma unroll
        for (int i = 0; i < 16; i++) {
            if ((i >> (3 - j)) & 1) m1 = fmaxf(m1, ex[i]);
            else                    m0 = fmaxf(m0, ex[i]);
        }
        float s1 = 0.f, s0 = 0.f;
        #pragma unroll
        for (int i = 0; i < 16; i++) {
            if ((i >> (3 - j)) & 1) s1 += __expf(ex[i] - m1);
            else                    s0 += __expf(ex[i] - m0);
        }
        res[j] = (m1 - m0) + (__logf(s1) - __logf(s0));
    }
    reinterpret_cast<float4*>(out + (size_t)site * 16)[g] =
        make_float4(res[0], res[1], res[2], res[3]);
}

extern "C" void kernel_launch(void* const* d_in, const int* in_sizes, int n_in,
                              void* d_out, int out_size, void* d_ws, size_t ws_size,
                              hipStream_t stream) {
    const float* y    = (const float*)d_in[0];
    const float* h    = (const float*)d_in[1];
    const float* llr  = (const float*)d_in[2];
    const float* no   = (const float*)d_in[3];
    float* out = (float*)d_out;
    int nsites = in_sizes[2] / 16;   // B*T*S = 196608
    int threads = 256;
    long long total = 4LL * nsites;  // 4 lanes per site
    int blocks = (int)((total + threads - 1) / threads);
    siso_pic_kernel<<<blocks, threads, 0, stream>>>(y, h, llr, no, out, nsites);
}